// Round 15
// baseline (1102.407 us; speedup 1.0000x reference)
//
#include <hip/hip_runtime.h>
#include <math.h>

#define NB 4096
#define NH 3
#define NK 32768
#define ND 128
#define KA 256           // A stored K: [rh(128) | rl(128)]
#define KB 256           // B stored K: [wh(128) | wl(128)]  (dedup: wh read twice via regs)
#define RB 128           // rows per block
#define CS 16            // column splits (2 per XCD)
#define CPB (NK / CS)    // 2048 cols per block
#define CI 128           // cols per col-iteration (4 col-groups x 32)
#define NCI (CPB / CI)   // 16 col-iterations per block (ci fits 4 bits)

typedef _Float16 half8_t __attribute__((ext_vector_type(8)));
typedef _Float16 half2_t __attribute__((ext_vector_type(2)));
typedef float f32x4 __attribute__((ext_vector_type(4)));
typedef __attribute__((address_space(1))) const unsigned int gu32_t;
typedef __attribute__((address_space(3))) unsigned int lu32_t;

// ---------------------------------------------------------------------------
// init: resid = inputs, quantized = 0, loss = 0, rr = sum(resid^2), Aext row.
__global__ __launch_bounds__(64) void init_kernel(const float* __restrict__ inp,
                                                  float* __restrict__ resid,
                                                  float* __restrict__ rr,
                                                  float* __restrict__ out,
                                                  _Float16* __restrict__ Aext) {
  int row = blockIdx.x;
  int lane = threadIdx.x;
  const float2* ip = (const float2*)(inp + row * ND);
  float2 v = ip[lane];
  ((float2*)(resid + row * ND))[lane] = v;
  ((float2*)(out + NB + row * ND))[lane] = make_float2(0.f, 0.f);
  if (lane == 0) out[row] = 0.f; // loss
  _Float16 h0 = (_Float16)v.x, h1 = (_Float16)v.y;
  _Float16 l0 = (_Float16)(v.x - (float)h0), l1 = (_Float16)(v.y - (float)h1);
  half2_t h = {h0, h1}, l = {l0, l1};
  _Float16* base = Aext + (size_t)row * KA;
  *(half2_t*)(base + 2 * lane) = h;       // rh
  *(half2_t*)(base + 128 + 2 * lane) = l; // rl
  float s = v.x * v.x + v.y * v.y;
  #pragma unroll
  for (int m = 32; m; m >>= 1) s += __shfl_xor(s, m, 64);
  if (lane == 0) rr[row] = s;
}

// ---------------------------------------------------------------------------
// norms[row] = sum(W[row]^2) for all H*K rows (one wave per row), fp32 exact.
// NOTE: do NOT change this reduction tree — its rounding order is what the
// reference-matching argmax ties were validated against.
__global__ __launch_bounds__(256) void norms_kernel(const float* __restrict__ emb,
                                                    float* __restrict__ norms) {
  int row = blockIdx.x * 4 + (threadIdx.x >> 6);
  int lane = threadIdx.x & 63;
  const float2* wp = (const float2*)(emb + (size_t)row * ND);
  float2 v = wp[lane];
  float s = v.x * v.x + v.y * v.y;
  #pragma unroll
  for (int m = 32; m; m >>= 1) s += __shfl_xor(s, m, 64);
  if (lane == 0) norms[row] = s;
}

// ---------------------------------------------------------------------------
// fp32 -> (hi,lo) fp16 split, ALL heads at once (emb is static), into the
// 16x16x32 kstep-major fragment layout WITHOUT the wh duplicate:
//   f16 offset = head*NK*KB + col64*16384 + ks*2048 + sub*512 + klo*128 + n_lo*8 + j
// ks 0..3 = wh chunks (k 0..127), ks 4..7 = wl chunks.
__global__ __launch_bounds__(256) void split_w_all_kernel(const float* __restrict__ emb,
                                                          _Float16* __restrict__ Bext) {
  const int head = blockIdx.x >> 11;      // 0..2
  const int cg = blockIdx.x & 2047;       // col group 0..2047 (16 cols each)
  const int n_lo = threadIdx.x & 15;
  const int c = threadIdx.x >> 4;         // 8-elem k-chunk 0..15 (k = c*8..)
  const int n = cg * 16 + n_lo;

  const float4* wp = (const float4*)(emb + (size_t)head * NK * ND + (size_t)n * ND + c * 8);
  float4 v0 = wp[0], v1 = wp[1];
  float xv[8] = {v0.x, v0.y, v0.z, v0.w, v1.x, v1.y, v1.z, v1.w};
  half8_t h, l;
  #pragma unroll
  for (int j = 0; j < 8; ++j) {
    _Float16 hh = (_Float16)xv[j];
    h[j] = hh;
    l[j] = (_Float16)(xv[j] - (float)hh);
  }
  const int ks0 = c >> 2; // 32-k chunk 0..3
  const int klo = c & 3;  // 8-chunk within the 32-k step
  _Float16* base = Bext + (size_t)head * NK * KB + (size_t)(cg >> 2) * 16384 +
                   (cg & 3) * 512 + klo * 128 + n_lo * 8;
  *(half8_t*)(base + ks0 * 2048) = h;       // wh  (ks 0..3)
  *(half8_t*)(base + (4 + ks0) * 2048) = l; // wl  (ks 4..7)
}

// ---------------------------------------------------------------------------
// Barrier-free score kernel — R15: champion (R8, 97.7us measured) + rolling
// B prefetch, paid for with a byte-packed index. R14 proved the prefetch
// mechanism at 256 thr but hit the (256,2) 128-reg wall (VGPR pinned 128,
// 15 MB spill, 110us). Here the base is R8 VERBATIM — 512 thr, (512,4)
// cap 128, RB=128, 8 waves = 2 row-halves x 4 col-groups, wave = 64r x 32c,
// acc[4][2], measured VGPR 64 — so the +16-reg prefetch buffer and the
// bi[16]->pkb[4] swap (-12) land at ~98 <= 128 with real slack (R9/R11
// spilled at ~130+; R14 at 118-vs-128).
// Changes vs R8 (each verified elsewhere):
//  1. rolling distance-1 B prefetch (R13/R14): consume (bh,bl) while
//     loading kc+1; kc3 prefetches NEXT ci's kc0 — its L2 latency hides
//     under the fold. Prologue load flies during the A-staging barrier.
//  2. bi[16] -> pkb[4], one byte per slot = (ci<<1)|tn (R12/R13 packing +
//     tn bit). Fold visits (ci desc, tn desc) => cidx strictly decreasing,
//     ">=" keeps lowest index; reconstruction in the epilogue is exact:
//     ii = colBase0 + wc*32 + l15 + (vb>>1)*CI + (vb&1)*16.
//  3. kc0 Z-peel (R14): first MFMA pair consumes a zero C-in, no acc init.
// B dedup unchanged: per 32-k chunk kc, 4 B loads feed 24 MFMAs; wh feeds
// TWO sets (A=rh, A=rl), wl one (A=rh). Numerics byte-identical.
// LDS 66 KB -> 2 blocks/CU; grid 512 = exactly 2/CU, tail-free.
// bid&15 = col-split; 2 x 1 MB B slices per XCD's L2 (cs mod 8 == xcd).
__global__ __launch_bounds__(512, 4) void score_mfma_kernel(
    const _Float16* __restrict__ Aext, const _Float16* __restrict__ Bext,
    const float* __restrict__ rr, const float* __restrict__ normh,
    float* __restrict__ partial_s, int* __restrict__ partial_i) {
  __shared__ __align__(16) _Float16 Ash[RB * KA]; // 64 KB: [p:4][m:128][slot:8][8 f16]
  __shared__ __align__(16) float rrsh[RB];        // 512 B

  const int bid = blockIdx.x;
  const int cs = bid & (CS - 1);
  const int rowb = bid >> 4;
  const int rowBase = rowb * RB;
  const int colBase0 = cs * CPB;

  const int tid = threadIdx.x;
  const int lane = tid & 63;
  const int wn = tid >> 6; // wave 0..7
  const int wc = wn & 3;   // col-group (32 cols)
  const int wr = wn >> 2;  // row-half (64 rows)
  const int l15 = lane & 15;
  const int q = lane >> 4;

  // ---- stage A panel [rh|rl] (once): wave wn stages 8 KB (R8-verified) --
  // LDS[p][m][slot] = A[rowBase+m][p*64 + (slot^(m&7))*8 ..+8]
  {
    const int p = wn >> 1;                  // panel 0..3 (64 k each)
    const int mh = (wn & 1) * 64;           // row half within panel
    const int mrow = lane >> 3;             // 0..7 within 8-row group
    const int cg = (lane & 7) ^ (mrow & 7); // global chunk this lane fetches
    #pragma unroll
    for (int i = 0; i < 8; ++i) {
      const int m0 = mh + i * 8; // 8-row group within the 128
      const _Float16* gA = Aext + (size_t)(rowBase + m0 + mrow) * KA + p * 64 + cg * 8;
      __builtin_amdgcn_global_load_lds((gu32_t*)gA, (lu32_t*)&Ash[(p * 128 + m0) * 64], 16, 0, 0);
    }
  }
  if (tid < RB) rrsh[tid] = rr[rowBase + tid];

  // per-lane A-fragment LDS byte addresses, even-kc parity (odd = ^64):
  // slot=(par*4+q)^(m&7); par flips byte bit6 carry-free (R8-verified).
  int aaddr0[4];
  #pragma unroll
  for (int mt = 0; mt < 4; ++mt) {
    const int m = wr * 64 + mt * 16 + l15;
    const int slot = q ^ (m & 7);
    aaddr0[mt] = (m * 8 + slot) * 16; // bytes within a p-panel
  }

  float bs[16];
  int pkb[4]; // 16 slots x byte: (ci<<1)|tn
  #pragma unroll
  for (int t = 0; t < 16; ++t) bs[t] = -INFINITY;
  #pragma unroll
  for (int t = 0; t < 4; ++t) pkb[t] = 0;

  // prologue: issue B(ci = NCI-1, kc0) — flies during the barrier wait
  unsigned bo;
  {
    const int ncol0 = colBase0 + (NCI - 1) * CI + wc * 32;
    bo = (unsigned)(ncol0 >> 6) * 16384u + (((unsigned)ncol0 >> 4) & 3u) * 512u +
         (unsigned)lane * 8u;
  }
  half8_t bh[2], bl[2];
  #pragma unroll
  for (int tn = 0; tn < 2; ++tn) {
    bh[tn] = *(const half8_t*)(Bext + bo + (unsigned)(tn * 512));
    bl[tn] = *(const half8_t*)(Bext + bo + (unsigned)(8192 + tn * 512));
  }

  __syncthreads(); // the only barrier before the epilogue

  const f32x4 Z = {0.f, 0.f, 0.f, 0.f};

  #pragma unroll 1
  for (int ci = NCI - 1; ci >= 0; --ci) {
    const int ncol = colBase0 + ci * CI + wc * 32;
    const int ci_n = (ci > 0) ? ci - 1 : 0;
    const int ncol_n = colBase0 + ci_n * CI + wc * 32;
    const unsigned bon = (unsigned)(ncol_n >> 6) * 16384u +
                         (((unsigned)ncol_n >> 4) & 3u) * 512u + (unsigned)lane * 8u;

    // normh for this ci, issued early; consumed by the fold at ci end
    float nw[2];
    #pragma unroll
    for (int tn = 0; tn < 2; ++tn) nw[tn] = normh[ncol + tn * 16 + l15];

    f32x4 acc[4][2];
    half8_t nh[2], nl[2];

    // ---- kc = 0, peeled: consume preloaded bh/bl with Z C-in; prefetch kc1
    {
      #pragma unroll
      for (int tn = 0; tn < 2; ++tn) {
        nh[tn] = *(const half8_t*)(Bext + bo + (unsigned)(2048 + tn * 512));
        nl[tn] = *(const half8_t*)(Bext + bo + (unsigned)(2048 + 8192 + tn * 512));
      }
      __builtin_amdgcn_s_setprio(1);
      #pragma unroll
      for (int mt = 0; mt < 4; ++mt) {
        const char* ap = (const char*)Ash + aaddr0[mt];
        half8_t ah = *(const half8_t*)ap;
        half8_t al = *(const half8_t*)(ap + 32768); // rl panels at +2 p-panels
        acc[mt][0] = __builtin_amdgcn_mfma_f32_16x16x32_f16(ah, bh[0], Z, 0, 0, 0);
        acc[mt][1] = __builtin_amdgcn_mfma_f32_16x16x32_f16(ah, bh[1], Z, 0, 0, 0);
        acc[mt][0] = __builtin_amdgcn_mfma_f32_16x16x32_f16(al, bh[0], acc[mt][0], 0, 0, 0);
        acc[mt][1] = __builtin_amdgcn_mfma_f32_16x16x32_f16(al, bh[1], acc[mt][1], 0, 0, 0);
        acc[mt][0] = __builtin_amdgcn_mfma_f32_16x16x32_f16(ah, bl[0], acc[mt][0], 0, 0, 0);
        acc[mt][1] = __builtin_amdgcn_mfma_f32_16x16x32_f16(ah, bl[1], acc[mt][1], 0, 0, 0);
      }
      __builtin_amdgcn_s_setprio(0);
      bh[0] = nh[0]; bh[1] = nh[1];
      bl[0] = nl[0]; bl[1] = nl[1];
    }

    // ---- kc = 1..3: consume kc, prefetch kc+1 (kc3 -> next ci's kc0) ----
    #pragma unroll
    for (int kc = 1; kc < 4; ++kc) {
      const unsigned po = (kc < 3) ? bo + (unsigned)((kc + 1) * 2048) : bon;
      #pragma unroll
      for (int tn = 0; tn < 2; ++tn) {
        nh[tn] = *(const half8_t*)(Bext + po + (unsigned)(tn * 512));
        nl[tn] = *(const half8_t*)(Bext + po + (unsigned)(8192 + tn * 512));
      }
      const int axor = (kc & 1) << 6;      // odd-kc slot parity
      const int abase = (kc >> 1) * 16384; // p-panel stride (128 rows x 128 B)
      __builtin_amdgcn_s_setprio(1);
      #pragma unroll
      for (int mt = 0; mt < 4; ++mt) {
        const char* ap = (const char*)Ash + ((aaddr0[mt] ^ axor) + abase);
        half8_t ah = *(const half8_t*)ap;
        half8_t al = *(const half8_t*)(ap + 32768);
        acc[mt][0] = __builtin_amdgcn_mfma_f32_16x16x32_f16(ah, bh[0], acc[mt][0], 0, 0, 0);
        acc[mt][1] = __builtin_amdgcn_mfma_f32_16x16x32_f16(ah, bh[1], acc[mt][1], 0, 0, 0);
        acc[mt][0] = __builtin_amdgcn_mfma_f32_16x16x32_f16(al, bh[0], acc[mt][0], 0, 0, 0);
        acc[mt][1] = __builtin_amdgcn_mfma_f32_16x16x32_f16(al, bh[1], acc[mt][1], 0, 0, 0);
        acc[mt][0] = __builtin_amdgcn_mfma_f32_16x16x32_f16(ah, bl[0], acc[mt][0], 0, 0, 0);
        acc[mt][1] = __builtin_amdgcn_mfma_f32_16x16x32_f16(ah, bl[1], acc[mt][1], 0, 0, 0);
      }
      __builtin_amdgcn_s_setprio(0);
      bh[0] = nh[0]; bh[1] = nh[1];
      bl[0] = nl[0]; bl[1] = nl[1];
    }

    // ---- fold into running argmax; next ci's kc0 B loads in flight
    // underneath. tn DESC + ci DESC => cidx strictly decreasing per slot,
    // so ">=" keeps the lowest index (matches jnp.argmax). Index stored as
    // one byte per slot: (ci<<1)|tn.
    #pragma unroll
    for (int tn = 1; tn >= 0; --tn) {
      const float nwv = nw[tn];
      const int valb = (ci << 1) | tn; // wave-uniform
      #pragma unroll
      for (int mt = 0; mt < 4; ++mt) {
        const f32x4 rvv = *(const f32x4*)&rrsh[wr * 64 + mt * 16 + q * 4];
        #pragma unroll
        for (int reg = 0; reg < 4; ++reg) {
          const int s = mt * 4 + reg;
          float t1 = rvv[reg] + nwv;                   // fl(rr + |w|^2), as ref
          float v = fmaf(2.0f, acc[mt][tn][reg], -t1); // == fl(2*acc - t1)
          bool u = (v >= bs[s]);
          bs[s] = u ? v : bs[s];
          const int sh = (s & 3) * 8;
          int upd = (pkb[s >> 2] & ~(0xFF << sh)) | (valb << sh);
          pkb[s >> 2] = u ? upd : pkb[s >> 2];
        }
      }
    }
    bo = bon;
  }

  // ---- block argmax reduction (overlay scratch on Ash) ----
  __syncthreads(); // all LDS A-reads complete
  float* red_s = (float*)Ash;      // [128][4]
  int* red_i = (int*)Ash + RB * 4; // [128][4]
  const int cb = colBase0 + wc * 32 + l15;
  #pragma unroll
  for (int t = 0; t < 16; ++t) {
    float s = bs[t];
    const int vb = (pkb[t >> 2] >> ((t & 3) * 8)) & 0xFF;
    int ii = cb + (vb >> 1) * CI + (vb & 1) * 16;
    #pragma unroll
    for (int mask = 1; mask <= 8; mask <<= 1) {
      float os = __shfl_xor(s, mask, 64);
      int oi = __shfl_xor(ii, mask, 64);
      if (os > s || (os == s && oi < ii)) { s = os; ii = oi; }
    }
    if (l15 == 0) {
      // row slot: wr*64 + mt*16 + q*4 + reg; column lane wc
      const int rloc = wr * 64 + (t >> 2) * 16 + q * 4 + (t & 3);
      red_s[rloc * 4 + wc] = s;
      red_i[rloc * 4 + wc] = ii;
    }
  }
  __syncthreads();
  if (tid < RB) {
    float s0 = red_s[tid * 4];
    int i0 = red_i[tid * 4];
    #pragma unroll
    for (int x = 1; x < 4; ++x) {
      float sx = red_s[tid * 4 + x];
      int ix = red_i[tid * 4 + x];
      if (sx > s0 || (sx == s0 && ix < i0)) { s0 = sx; i0 = ix; }
    }
    partial_s[(size_t)(rowBase + tid) * CS + cs] = s0;
    partial_i[(size_t)(rowBase + tid) * CS + cs] = i0;
  }
}

// ---------------------------------------------------------------------------
// Combine col-split partials -> code; resid -= W[c]; quantized += W[c];
// new rr; Aext row for next head.
__global__ __launch_bounds__(64) void reduce_update_kernel(const float* __restrict__ embh,
                                                           float* __restrict__ resid,
                                                           float* __restrict__ rr,
                                                           const float* __restrict__ ps,
                                                           const int* __restrict__ pi,
                                                           float* __restrict__ out,
                                                           _Float16* __restrict__ Aext, int h) {
  int row = blockIdx.x;
  int lane = threadIdx.x;
  float bs = -INFINITY;
  int bi = 0x7fffffff;
  if (lane < CS) {
    bs = ps[(size_t)row * CS + lane];
    bi = pi[(size_t)row * CS + lane];
  }
  #pragma unroll
  for (int m = 8; m; m >>= 1) {
    float os = __shfl_xor(bs, m, 64);
    int oi = __shfl_xor(bi, m, 64);
    if (os > bs || (os == bs && oi < bi)) { bs = os; bi = oi; }
  }
  int c = __shfl(bi, 0, 64);
  if (lane == 0) out[NB + NB * ND + row * NH + h] = (float)c; // codes as f32

  const float* wv = embh + (size_t)c * ND;
  float q0 = wv[lane], q1 = wv[lane + 64];
  float r0 = resid[row * ND + lane] - q0;
  float r1 = resid[row * ND + lane + 64] - q1;
  resid[row * ND + lane] = r0;
  resid[row * ND + lane + 64] = r1;
  out[NB + row * ND + lane] += q0;
  out[NB + row * ND + lane + 64] += q1;

  // Aext row for the next head (harmless extra work on the last head)
  _Float16 h0 = (_Float16)r0, l0 = (_Float16)(r0 - (float)h0);
  _Float16 h1 = (_Float16)r1, l1 = (_Float16)(r1 - (float)h1);
  _Float16* ab = Aext + (size_t)row * KA;
  ab[lane] = h0;       ab[lane + 64] = h1;       // rh
  ab[128 + lane] = l0; ab[128 + lane + 64] = l1; // rl

  float s = r0 * r0 + r1 * r1;
  #pragma unroll
  for (int m = 32; m; m >>= 1) s += __shfl_xor(s, m, 64);
  if (lane == 0) rr[row] = s;
}

// ---------------------------------------------------------------------------
extern "C" void kernel_launch(void* const* d_in, const int* in_sizes, int n_in,
                              void* d_out, int out_size, void* d_ws, size_t ws_size,
                              hipStream_t stream) {
  const float* inp = (const float*)d_in[0]; // (4096,1,128)
  const float* emb = (const float*)d_in[1]; // (3,32768,128)
  float* out = (float*)d_out;               // loss | quantized | codes

  float* resid = (float*)d_ws;                        // NB*ND f32
  float* rr = resid + NB * ND;                        // NB
  float* norms = rr + NB;                             // NH*NK
  float* ps = norms + NH * NK;                        // NB*CS f32
  int* pi = (int*)(ps + (size_t)NB * CS);             // NB*CS i32
  _Float16* Aext = (_Float16*)(pi + (size_t)NB * CS); // NB*KA f16
  _Float16* Bext = Aext + (size_t)NB * KA;            // NH*NK*KB f16 (~50 MB)

  hipLaunchKernelGGL(init_kernel, dim3(NB), dim3(64), 0, stream, inp, resid, rr, out, Aext);
  hipLaunchKernelGGL(norms_kernel, dim3(NH * NK / 4), dim3(256), 0, stream, emb, norms);
  hipLaunchKernelGGL(split_w_all_kernel, dim3(NH * NK / 16), dim3(256), 0, stream, emb, Bext);
  for (int h = 0; h < NH; ++h) {
    hipLaunchKernelGGL(score_mfma_kernel, dim3((NB / RB) * CS), dim3(512), 0, stream,
                       Aext, Bext + (size_t)h * NK * KB, rr, norms + (size_t)h * NK, ps, pi);
    hipLaunchKernelGGL(reduce_update_kernel, dim3(NB), dim3(64), 0, stream,
                       emb + (size_t)h * NK * ND, resid, rr, ps, pi, out, Aext, h);
  }
}

// Round 16
// 415.213 us; speedup vs baseline: 2.6550x; 2.6550x over previous
//
#include <hip/hip_runtime.h>
#include <math.h>

#define NB 4096
#define NH 3
#define NK 32768
#define ND 128
#define KA 256           // A stored K: [rh(128) | rl(128)]
#define KB 256           // B stored K: [wh(128) | wl(128)]  (dedup: wh read twice via regs)
#define RB 64            // rows per block (32.5 KB LDS -> 4 blocks/CU resident)
#define CS 16            // column splits (2 per XCD)
#define CPB (NK / CS)    // 2048 cols per block
#define CI 128           // cols per col-iteration (4 waves x 32)
#define NCI (CPB / CI)   // 16 col-iterations per block (ci fits 4 bits)

typedef _Float16 half8_t __attribute__((ext_vector_type(8)));
typedef _Float16 half2_t __attribute__((ext_vector_type(2)));
typedef float f32x4 __attribute__((ext_vector_type(4)));
typedef __attribute__((address_space(1))) const unsigned int gu32_t;
typedef __attribute__((address_space(3))) unsigned int lu32_t;

// ---------------------------------------------------------------------------
// init: resid = inputs, quantized = 0, loss = 0, rr = sum(resid^2), Aext row.
__global__ __launch_bounds__(64) void init_kernel(const float* __restrict__ inp,
                                                  float* __restrict__ resid,
                                                  float* __restrict__ rr,
                                                  float* __restrict__ out,
                                                  _Float16* __restrict__ Aext) {
  int row = blockIdx.x;
  int lane = threadIdx.x;
  const float2* ip = (const float2*)(inp + row * ND);
  float2 v = ip[lane];
  ((float2*)(resid + row * ND))[lane] = v;
  ((float2*)(out + NB + row * ND))[lane] = make_float2(0.f, 0.f);
  if (lane == 0) out[row] = 0.f; // loss
  _Float16 h0 = (_Float16)v.x, h1 = (_Float16)v.y;
  _Float16 l0 = (_Float16)(v.x - (float)h0), l1 = (_Float16)(v.y - (float)h1);
  half2_t h = {h0, h1}, l = {l0, l1};
  _Float16* base = Aext + (size_t)row * KA;
  *(half2_t*)(base + 2 * lane) = h;       // rh
  *(half2_t*)(base + 128 + 2 * lane) = l; // rl
  float s = v.x * v.x + v.y * v.y;
  #pragma unroll
  for (int m = 32; m; m >>= 1) s += __shfl_xor(s, m, 64);
  if (lane == 0) rr[row] = s;
}

// ---------------------------------------------------------------------------
// norms[row] = sum(W[row]^2) for all H*K rows (one wave per row), fp32 exact.
// NOTE: do NOT change this reduction tree — its rounding order is what the
// reference-matching argmax ties were validated against.
__global__ __launch_bounds__(256) void norms_kernel(const float* __restrict__ emb,
                                                    float* __restrict__ norms) {
  int row = blockIdx.x * 4 + (threadIdx.x >> 6);
  int lane = threadIdx.x & 63;
  const float2* wp = (const float2*)(emb + (size_t)row * ND);
  float2 v = wp[lane];
  float s = v.x * v.x + v.y * v.y;
  #pragma unroll
  for (int m = 32; m; m >>= 1) s += __shfl_xor(s, m, 64);
  if (lane == 0) norms[row] = s;
}

// ---------------------------------------------------------------------------
// fp32 -> (hi,lo) fp16 split, ALL heads at once (emb is static), into the
// 16x16x32 kstep-major fragment layout WITHOUT the wh duplicate:
//   f16 offset = head*NK*KB + col64*16384 + ks*2048 + sub*512 + klo*128 + n_lo*8 + j
// ks 0..3 = wh chunks (k 0..127), ks 4..7 = wl chunks.
__global__ __launch_bounds__(256) void split_w_all_kernel(const float* __restrict__ emb,
                                                          _Float16* __restrict__ Bext) {
  const int head = blockIdx.x >> 11;      // 0..2
  const int cg = blockIdx.x & 2047;       // col group 0..2047 (16 cols each)
  const int n_lo = threadIdx.x & 15;
  const int c = threadIdx.x >> 4;         // 8-elem k-chunk 0..15 (k = c*8..)
  const int n = cg * 16 + n_lo;

  const float4* wp = (const float4*)(emb + (size_t)head * NK * ND + (size_t)n * ND + c * 8);
  float4 v0 = wp[0], v1 = wp[1];
  float xv[8] = {v0.x, v0.y, v0.z, v0.w, v1.x, v1.y, v1.z, v1.w};
  half8_t h, l;
  #pragma unroll
  for (int j = 0; j < 8; ++j) {
    _Float16 hh = (_Float16)xv[j];
    h[j] = hh;
    l[j] = (_Float16)(xv[j] - (float)hh);
  }
  const int ks0 = c >> 2; // 32-k chunk 0..3
  const int klo = c & 3;  // 8-chunk within the 32-k step
  _Float16* base = Bext + (size_t)head * NK * KB + (size_t)(cg >> 2) * 16384 +
                   (cg & 3) * 512 + klo * 128 + n_lo * 8;
  *(half8_t*)(base + ks0 * 2048) = h;       // wh  (ks 0..3)
  *(half8_t*)(base + (4 + ks0) * 2048) = l; // wl  (ks 4..7)
}

// ---------------------------------------------------------------------------
// Barrier-free score kernel — R16: R14 + byte-packed index (the 12-reg fix).
// Ledger: (512,4) caps arch VGPR at 64 (R8 fits exactly; R9/R11/R15 all
// spilled — 4 data points, door closed). (256,2) caps at 128; R14 (this
// geometry + prefetch, bi[16]) measured demand ~134: VGPR pinned 128, 15 MB
// spill, yet still 110us — prefetch works under the spill. pkb packing
// (R15-verified correct, absmax=0) saves exactly 12 regs -> ~122 < 128.
// Geometry (R14): 256 thr (256,2), 4 waves each 64r x 32c (wave = col
// group), RB=64 -> LDS 32.5 KB -> 4 blocks/CU target, grid 1024 tail-free;
// co-resident blocks share one cs (256%16==0) -> one 1 MB B slice per CU.
// Mechanics (each verified): rolling distance-1 B prefetch incl. across-ci
// (fold covers next ci's kc0; R13/R14); kc0 Z-peel (R14); rv->rrsh LDS;
// aaddr odd parity = even ^ 64 (R5); byte index (ci<<1)|tn with ci-desc/
// tn-desc fold => cidx strictly decreasing, ">=" keeps lowest (R15).
// B dedup: per 32-k chunk kc, 4 B loads feed 24 MFMAs; wh feeds TWO sets
// (A=rh, A=rl), wl one (A=rh). Numerics byte-identical to R0/R8.
// bid&15 = col-split; 2 x 1 MB B slices per XCD's L2 (cs mod 8 == xcd).
__global__ __launch_bounds__(256, 2) void score_mfma_kernel(
    const _Float16* __restrict__ Aext, const _Float16* __restrict__ Bext,
    const float* __restrict__ rr, const float* __restrict__ normh,
    float* __restrict__ partial_s, int* __restrict__ partial_i) {
  __shared__ __align__(16) _Float16 Ash[RB * KA]; // 32 KB
  __shared__ __align__(16) float rrsh[RB];        // 256 B

  const int bid = blockIdx.x;
  const int cs = bid & (CS - 1);
  const int rowb = bid >> 4;
  const int rowBase = rowb * RB;
  const int colBase0 = cs * CPB;

  const int tid = threadIdx.x;
  const int lane = tid & 63;
  const int wn = tid >> 6; // wave = col group 0..3
  const int l15 = lane & 15;
  const int q = lane >> 4;

  // ---- stage A panel [rh|rl] (once) — R0-verified staging ----
  {
    const int mrow = lane >> 3;             // 0..7 within 8-row group
    const int cg = (lane & 7) ^ (mrow & 7); // chunk this lane fetches
    #pragma unroll
    for (int i = 0; i < 8; ++i) {
      int wc = wn * 8 + i; // 0..31 wave-chunks (1 KB each)
      int p = wc >> 3;     // panel 0..3 (64 k each)
      int m0 = (wc & 7) * 8;
      const _Float16* gA = Aext + (size_t)(rowBase + m0 + mrow) * KA + p * 64 + cg * 8;
      __builtin_amdgcn_global_load_lds((gu32_t*)gA, (lu32_t*)&Ash[(p * 64 + m0) * 64], 16, 0, 0);
    }
  }
  if (tid < RB) rrsh[tid] = rr[rowBase + tid];

  // per-lane A-fragment LDS byte addresses, even-kc parity (odd = ^64):
  // slot=(par*4+q)^(m&7); par flips byte bit6 carry-free (R5-verified).
  int aaddr0[4];
  #pragma unroll
  for (int mt = 0; mt < 4; ++mt) {
    int m = mt * 16 + l15;
    int slot = q ^ (m & 7);
    aaddr0[mt] = (m * 8 + slot) * 16; // bytes
  }

  float bs[16];
  int pkb[4]; // 16 slots x byte: (ci<<1)|tn
  #pragma unroll
  for (int t = 0; t < 16; ++t) bs[t] = -INFINITY;
  #pragma unroll
  for (int t = 0; t < 4; ++t) pkb[t] = 0;

  // prologue: issue B(ci = NCI-1, kc0) — flies during the barrier
  unsigned bo = (unsigned)((colBase0 + (NCI - 1) * CI + wn * 32) >> 6) * 16384u +
                (((unsigned)(colBase0 + (NCI - 1) * CI + wn * 32) >> 4) & 3u) * 512u +
                (unsigned)lane * 8u;
  half8_t bh[2], bl[2];
  #pragma unroll
  for (int tn = 0; tn < 2; ++tn) {
    bh[tn] = *(const half8_t*)(Bext + bo + (unsigned)(tn * 512));
    bl[tn] = *(const half8_t*)(Bext + bo + (unsigned)(8192 + tn * 512));
  }

  __syncthreads(); // the only barrier before the epilogue

  const f32x4 Z = {0.f, 0.f, 0.f, 0.f};

  #pragma unroll 1
  for (int ci = NCI - 1; ci >= 0; --ci) {
    const int ncol = colBase0 + ci * CI + wn * 32;
    const int ci_n = (ci > 0) ? ci - 1 : 0;
    const int ncol_n = colBase0 + ci_n * CI + wn * 32;
    const unsigned bon = (unsigned)(ncol_n >> 6) * 16384u +
                         (((unsigned)ncol_n >> 4) & 3u) * 512u + (unsigned)lane * 8u;

    // normh for this ci, issued early; consumed by the fold at ci end
    float nw[2];
    #pragma unroll
    for (int tn = 0; tn < 2; ++tn) nw[tn] = normh[ncol + tn * 16 + l15];

    f32x4 acc[4][2];
    half8_t nh[2], nl[2];

    // ---- kc = 0, peeled: consume preloaded bh/bl with Z C-in; prefetch kc1
    {
      #pragma unroll
      for (int tn = 0; tn < 2; ++tn) {
        nh[tn] = *(const half8_t*)(Bext + bo + (unsigned)(2048 + tn * 512));
        nl[tn] = *(const half8_t*)(Bext + bo + (unsigned)(2048 + 8192 + tn * 512));
      }
      __builtin_amdgcn_s_setprio(1);
      #pragma unroll
      for (int mt = 0; mt < 4; ++mt) {
        half8_t ah = *(const half8_t*)((const char*)Ash + aaddr0[mt]);
        half8_t al = *(const half8_t*)((const char*)Ash + aaddr0[mt] + 16384);
        acc[mt][0] = __builtin_amdgcn_mfma_f32_16x16x32_f16(ah, bh[0], Z, 0, 0, 0);
        acc[mt][1] = __builtin_amdgcn_mfma_f32_16x16x32_f16(ah, bh[1], Z, 0, 0, 0);
        acc[mt][0] = __builtin_amdgcn_mfma_f32_16x16x32_f16(al, bh[0], acc[mt][0], 0, 0, 0);
        acc[mt][1] = __builtin_amdgcn_mfma_f32_16x16x32_f16(al, bh[1], acc[mt][1], 0, 0, 0);
        acc[mt][0] = __builtin_amdgcn_mfma_f32_16x16x32_f16(ah, bl[0], acc[mt][0], 0, 0, 0);
        acc[mt][1] = __builtin_amdgcn_mfma_f32_16x16x32_f16(ah, bl[1], acc[mt][1], 0, 0, 0);
      }
      __builtin_amdgcn_s_setprio(0);
      bh[0] = nh[0]; bh[1] = nh[1];
      bl[0] = nl[0]; bl[1] = nl[1];
    }

    // ---- kc = 1..3: consume kc, prefetch kc+1 (kc3 -> next ci's kc0) ----
    #pragma unroll
    for (int kc = 1; kc < 4; ++kc) {
      const unsigned po = (kc < 3) ? bo + (unsigned)((kc + 1) * 2048) : bon;
      #pragma unroll
      for (int tn = 0; tn < 2; ++tn) {
        nh[tn] = *(const half8_t*)(Bext + po + (unsigned)(tn * 512));
        nl[tn] = *(const half8_t*)(Bext + po + (unsigned)(8192 + tn * 512));
      }
      const int axor = (kc & 1) << 6;
      const int abase = (kc >> 1) * 8192;
      __builtin_amdgcn_s_setprio(1);
      #pragma unroll
      for (int mt = 0; mt < 4; ++mt) {
        half8_t ah = *(const half8_t*)((const char*)Ash + ((aaddr0[mt] ^ axor) + abase));
        half8_t al = *(const half8_t*)((const char*)Ash + ((aaddr0[mt] ^ axor) + abase + 16384));
        acc[mt][0] = __builtin_amdgcn_mfma_f32_16x16x32_f16(ah, bh[0], acc[mt][0], 0, 0, 0);
        acc[mt][1] = __builtin_amdgcn_mfma_f32_16x16x32_f16(ah, bh[1], acc[mt][1], 0, 0, 0);
        acc[mt][0] = __builtin_amdgcn_mfma_f32_16x16x32_f16(al, bh[0], acc[mt][0], 0, 0, 0);
        acc[mt][1] = __builtin_amdgcn_mfma_f32_16x16x32_f16(al, bh[1], acc[mt][1], 0, 0, 0);
        acc[mt][0] = __builtin_amdgcn_mfma_f32_16x16x32_f16(ah, bl[0], acc[mt][0], 0, 0, 0);
        acc[mt][1] = __builtin_amdgcn_mfma_f32_16x16x32_f16(ah, bl[1], acc[mt][1], 0, 0, 0);
      }
      __builtin_amdgcn_s_setprio(0);
      bh[0] = nh[0]; bh[1] = nh[1];
      bl[0] = nl[0]; bl[1] = nl[1];
    }

    // ---- fold into running argmax; next ci's kc0 B loads are in flight
    // underneath. tn DESC + ci DESC => cidx strictly decreasing per slot,
    // ">=" keeps the lowest index (matches jnp.argmax). Index stored as
    // one byte per slot: (ci<<1)|tn (R15-verified).
    #pragma unroll
    for (int tn = 1; tn >= 0; --tn) {
      const float nwv = nw[tn];
      const int valb = (ci << 1) | tn; // wave-uniform
      #pragma unroll
      for (int mt = 0; mt < 4; ++mt) {
        const f32x4 rvv = *(const f32x4*)&rrsh[mt * 16 + q * 4];
        #pragma unroll
        for (int reg = 0; reg < 4; ++reg) {
          const int s = mt * 4 + reg;
          float t1 = rvv[reg] + nwv;                   // fl(rr + |w|^2), as ref
          float v = fmaf(2.0f, acc[mt][tn][reg], -t1); // == fl(2*acc - t1)
          bool u = (v >= bs[s]);
          bs[s] = u ? v : bs[s];
          const int sh = (s & 3) * 8;
          int upd = (pkb[s >> 2] & ~(0xFF << sh)) | (valb << sh);
          pkb[s >> 2] = u ? upd : pkb[s >> 2];
        }
      }
    }
    bo = bon;
  }

  // ---- block argmax reduction (overlay scratch on Ash) ----
  __syncthreads(); // all LDS A-reads complete
  float* red_s = (float*)Ash;      // [64][4]
  int* red_i = (int*)Ash + RB * 4; // [64][4]
  const int cb = colBase0 + wn * 32 + l15;
  #pragma unroll
  for (int t = 0; t < 16; ++t) {
    float s = bs[t];
    const int vb = (pkb[t >> 2] >> ((t & 3) * 8)) & 0xFF;
    int ii = cb + (vb >> 1) * CI + (vb & 1) * 16;
    #pragma unroll
    for (int mask = 1; mask <= 8; mask <<= 1) {
      float os = __shfl_xor(s, mask, 64);
      int oi = __shfl_xor(ii, mask, 64);
      if (os > s || (os == s && oi < ii)) { s = os; ii = oi; }
    }
    if (l15 == 0) {
      int rloc = (t >> 2) * 16 + q * 4 + (t & 3); // mt*16 + q*4 + reg
      red_s[rloc * 4 + wn] = s;
      red_i[rloc * 4 + wn] = ii;
    }
  }
  __syncthreads();
  if (tid < RB) {
    float s0 = red_s[tid * 4];
    int i0 = red_i[tid * 4];
    #pragma unroll
    for (int x = 1; x < 4; ++x) {
      float sx = red_s[tid * 4 + x];
      int ix = red_i[tid * 4 + x];
      if (sx > s0 || (sx == s0 && ix < i0)) { s0 = sx; i0 = ix; }
    }
    partial_s[(size_t)(rowBase + tid) * CS + cs] = s0;
    partial_i[(size_t)(rowBase + tid) * CS + cs] = i0;
  }
}

// ---------------------------------------------------------------------------
// Combine col-split partials -> code; resid -= W[c]; quantized += W[c];
// new rr; Aext row for next head.
__global__ __launch_bounds__(64) void reduce_update_kernel(const float* __restrict__ embh,
                                                           float* __restrict__ resid,
                                                           float* __restrict__ rr,
                                                           const float* __restrict__ ps,
                                                           const int* __restrict__ pi,
                                                           float* __restrict__ out,
                                                           _Float16* __restrict__ Aext, int h) {
  int row = blockIdx.x;
  int lane = threadIdx.x;
  float bs = -INFINITY;
  int bi = 0x7fffffff;
  if (lane < CS) {
    bs = ps[(size_t)row * CS + lane];
    bi = pi[(size_t)row * CS + lane];
  }
  #pragma unroll
  for (int m = 8; m; m >>= 1) {
    float os = __shfl_xor(bs, m, 64);
    int oi = __shfl_xor(bi, m, 64);
    if (os > bs || (os == bs && oi < bi)) { bs = os; bi = oi; }
  }
  int c = __shfl(bi, 0, 64);
  if (lane == 0) out[NB + NB * ND + row * NH + h] = (float)c; // codes as f32

  const float* wv = embh + (size_t)c * ND;
  float q0 = wv[lane], q1 = wv[lane + 64];
  float r0 = resid[row * ND + lane] - q0;
  float r1 = resid[row * ND + lane + 64] - q1;
  resid[row * ND + lane] = r0;
  resid[row * ND + lane + 64] = r1;
  out[NB + row * ND + lane] += q0;
  out[NB + row * ND + lane + 64] += q1;

  // Aext row for the next head (harmless extra work on the last head)
  _Float16 h0 = (_Float16)r0, l0 = (_Float16)(r0 - (float)h0);
  _Float16 h1 = (_Float16)r1, l1 = (_Float16)(r1 - (float)h1);
  _Float16* ab = Aext + (size_t)row * KA;
  ab[lane] = h0;       ab[lane + 64] = h1;       // rh
  ab[128 + lane] = l0; ab[128 + lane + 64] = l1; // rl

  float s = r0 * r0 + r1 * r1;
  #pragma unroll
  for (int m = 32; m; m >>= 1) s += __shfl_xor(s, m, 64);
  if (lane == 0) rr[row] = s;
}

// ---------------------------------------------------------------------------
extern "C" void kernel_launch(void* const* d_in, const int* in_sizes, int n_in,
                              void* d_out, int out_size, void* d_ws, size_t ws_size,
                              hipStream_t stream) {
  const float* inp = (const float*)d_in[0]; // (4096,1,128)
  const float* emb = (const float*)d_in[1]; // (3,32768,128)
  float* out = (float*)d_out;               // loss | quantized | codes

  float* resid = (float*)d_ws;                        // NB*ND f32
  float* rr = resid + NB * ND;                        // NB
  float* norms = rr + NB;                             // NH*NK
  float* ps = norms + NH * NK;                        // NB*CS f32
  int* pi = (int*)(ps + (size_t)NB * CS);             // NB*CS i32
  _Float16* Aext = (_Float16*)(pi + (size_t)NB * CS); // NB*KA f16
  _Float16* Bext = Aext + (size_t)NB * KA;            // NH*NK*KB f16 (~50 MB)

  hipLaunchKernelGGL(init_kernel, dim3(NB), dim3(64), 0, stream, inp, resid, rr, out, Aext);
  hipLaunchKernelGGL(norms_kernel, dim3(NH * NK / 4), dim3(256), 0, stream, emb, norms);
  hipLaunchKernelGGL(split_w_all_kernel, dim3(NH * NK / 16), dim3(256), 0, stream, emb, Bext);
  for (int h = 0; h < NH; ++h) {
    hipLaunchKernelGGL(score_mfma_kernel, dim3((NB / RB) * CS), dim3(256), 0, stream,
                       Aext, Bext + (size_t)h * NK * KB, rr, norms + (size_t)h * NK, ps, pi);
    hipLaunchKernelGGL(reduce_update_kernel, dim3(NB), dim3(64), 0, stream,
                       emb + (size_t)h * NK * ND, resid, rr, ps, pi, out, Aext, h);
  }
}